// Round 7
// baseline (500.199 us; speedup 1.0000x reference)
//
#include <hip/hip_runtime.h>
#include <cmath>

#define N_AG 2048
#define HID  2048
#define OBSD 1024
#define ACT  64
#define GATES (4*HID)   // 8192

typedef short s16x8 __attribute__((ext_vector_type(8)));
typedef short s16x4 __attribute__((ext_vector_type(4)));
typedef float f32x4 __attribute__((ext_vector_type(4)));

__device__ __forceinline__ unsigned short f2bf(float f) {
  union { float f; unsigned u; } v; v.f = f;
  return (unsigned short)((v.u + 0x7FFFu + ((v.u >> 16) & 1u)) >> 16);
}
__device__ __forceinline__ float bf2f(unsigned short u) {
  union { float f; unsigned u; } v; v.u = ((unsigned)u) << 16;
  return v.f;
}
// Fast transcendentals: native v_exp_f32 + v_rcp_f32. Overflow-safe at all x
// (exp->inf => rcp=0 => correct saturation).
__device__ __forceinline__ float fsigm(float x) {
  return __builtin_amdgcn_rcpf(1.0f + __expf(-x));
}
__device__ __forceinline__ float ftanh(float x) {
  return 2.0f * __builtin_amdgcn_rcpf(1.0f + __expf(-2.0f * x)) - 1.0f;
}

// async global->LDS DMA, 16B per lane; LDS dest = wave-uniform base + lane*16
__device__ __forceinline__ void gload16(const unsigned short* g, unsigned short* l) {
  __builtin_amdgcn_global_load_lds(
      (const __attribute__((address_space(1))) void*)g,
      (__attribute__((address_space(3))) void*)l, 16, 0, 0);
}

// Gate-interleaved column index: c = (hid>>4)*64 + g*16 + (hid&15).
// Inverse: g = (c>>4)&3, hid = ((c>>6)<<4) | (c&15).
// Within a wave's 64-col strip the 4 gates of one hid sit at nf=0..3, SAME l16 ->
// the LSTM pointwise is per-lane in the GEMM epilogue (no cross-lane traffic).

// =====================================================================================
// 256x256 bf16 GEMM + fused LSTM epilogue + fused comm column-sum.
// C = A(MxK,row) * B(NxK,row)^T. 512 thr = 8 waves (2M x 4N), BK=64, LDS dbuf, 1 blk/CU.
// R6/R7: (1) XCD swizzle: HW XCD = lin%8; remap by_s = lin&7, bx_s = lin>>3 so each
//     XCD owns ONE A-row-panel (1MB, L2-resident). Bijective (256%8==0). Packed
//     E1b/cell keyed on lin (same mapping in all 3 fused dispatches -> consistent).
// (2) hN store via LDS bounce: stage 256x64 bf16 tile in As (free after K-loop),
//     then 2048 contiguous 16B chunk stores (4/thread) vs 16384 scattered 2B stores.
// R7 fix: PB_WHD was 128 (half of build_whd's 256 blocks) -> Whd rows 64..127 were
//     stale garbage -> value output wrong. PB_WHD = 256.
// MODE 10 (iter 0): store E1 (packed); LSTM c_old=0, z=acc+bc; write cell, hN.
// MODE 11 (iters 1,2): z = acc + E1 + q + bc; LSTM step; write cell, hN.
// ACCS: S[hid] += alive[ag]*h_new (quad-reduced, 1 atomic/4 lanes).
// =====================================================================================
template <int MODE, int ACCS>
__global__ __launch_bounds__(512, 2) void gemm256(
    const unsigned short* __restrict__ A, const unsigned short* __restrict__ B,
    int K, int lda, int ldb,
    unsigned short* __restrict__ E1b, const float* __restrict__ q,
    const float* __restrict__ bc, float* __restrict__ cell,
    unsigned short* __restrict__ hN,
    const float* __restrict__ alive, float* __restrict__ S)
{
  __shared__ __align__(16) unsigned short As[32768];  // 64 KiB
  __shared__ __align__(16) unsigned short Bs[32768];  // 64 KiB

  const int tid  = threadIdx.x;
  const int lane = tid & 63;
  const int wave = tid >> 6;                 // 0..7
  const int wm   = wave >> 2, wn = wave & 3; // 2M x 4N wave grid
  const int quad = lane >> 4, l16 = lane & 15, r7 = lane & 7;
  // XCD swizzle (T1): dispatch-linear id; XCD = lin % 8 -> by_s = lin&7
  const int lin  = (int)blockIdx.x + (int)blockIdx.y * (int)gridDim.x;
  const long tileM = (long)(lin & 7) * 256;
  const long tileN = (long)(lin >> 3) * 256;

  // staging; col pre-swizzled: global col-block (lane&7)^(lane>>3) -> LDS slot g^(row&7)
  const unsigned scol  = (((lane & 7) ^ (lane >> 3)) * 8u);
  const unsigned aoffL = (unsigned)(tileM + wave * 8 + (lane >> 3)) * (unsigned)lda + scol;
  const unsigned boffL = (unsigned)(tileN + (wave >> 2) * 64 + (wave & 3) * 8 + (lane >> 3))
                           * (unsigned)ldb + scol;

#define ST_A(d, h, t) { \
    gload16(A + aoffL + (unsigned)((h) * 64) * (unsigned)lda + (unsigned)(t) * 64u, \
            &As[(d) * 16384 + (h) * 8192 + wave * 512]); \
    gload16(A + aoffL + (unsigned)(128 + (h) * 64) * (unsigned)lda + (unsigned)(t) * 64u, \
            &As[(d) * 16384 + (h) * 8192 + wave * 512 + 4096]); }
#define ST_B(d, h, t) { \
    gload16(B + boffL + (unsigned)((h) * 32) * (unsigned)ldb + (unsigned)(t) * 64u, \
            &Bs[(d) * 16384 + (h) * 8192 + wave * 512]); \
    gload16(B + boffL + (unsigned)(128 + (h) * 32) * (unsigned)ldb + (unsigned)(t) * 64u, \
            &Bs[(d) * 16384 + (h) * 8192 + wave * 512 + 4096]); }

  const int ax = wm * 4096 + l16 * 64;       // within A half region (elems)
  const int bx = wn * 2048 + l16 * 64;       // within B half region
  const int c0 = (quad ^ r7) * 8;            // swizzled col, K-step 0
  const int c1 = ((4 + quad) ^ r7) * 8;      // swizzled col, K-step 1

  s16x8 af0[4][2], af1[4][2], bA[2][2], bB[2][2];
  f32x4 acc[8][4] = {};

#define LD_A(d, Mh, dst) { const unsigned short* p_ = &As[(d) * 16384 + (Mh) * 8192 + ax]; \
    _Pragma("unroll") for (int ml = 0; ml < 4; ++ml) { \
      dst[ml][0] = *(const s16x8*)(p_ + ml * 1024 + c0); \
      dst[ml][1] = *(const s16x8*)(p_ + ml * 1024 + c1); } }
#define LD_B(d, Nh, dst) { const unsigned short* p_ = &Bs[(d) * 16384 + (Nh) * 8192 + bx]; \
    _Pragma("unroll") for (int nl = 0; nl < 2; ++nl) { \
      dst[nl][0] = *(const s16x8*)(p_ + nl * 1024 + c0); \
      dst[nl][1] = *(const s16x8*)(p_ + nl * 1024 + c1); } }
#define QMM(Mh, Nh, afv, bb) \
    _Pragma("unroll") for (int ks = 0; ks < 2; ++ks) \
    _Pragma("unroll") for (int ml = 0; ml < 4; ++ml) \
    _Pragma("unroll") for (int nl = 0; nl < 2; ++nl) \
      acc[(Mh) * 4 + ml][(Nh) * 2 + nl] = __builtin_amdgcn_mfma_f32_16x16x32_bf16( \
          afv[ml][ks], bb[nl][ks], acc[(Mh) * 4 + ml][(Nh) * 2 + nl], 0, 0, 0);
#define BAR  __builtin_amdgcn_s_barrier()
#define SCHB __builtin_amdgcn_sched_barrier(0)

  const int NT = K >> 6;   // K-tiles of 64

  ST_B(0, 0, 0); ST_A(0, 0, 0); ST_B(0, 1, 0); ST_A(0, 1, 0);
  asm volatile("s_waitcnt vmcnt(0)" ::: "memory");
  BAR;
  LD_A(0, 0, af0); LD_B(0, 0, bA);

  for (int t = 0; t < NT; ++t) {
    const int cur = t & 1, nxt = cur ^ 1;
    const bool s1 = (t + 1 < NT);
    LD_B(cur, 1, bB);
    if (s1) { ST_B(nxt, 0, t + 1); ST_A(nxt, 0, t + 1); }
    SCHB;
    __builtin_amdgcn_s_setprio(1); QMM(0, 0, af0, bA); __builtin_amdgcn_s_setprio(0);
    if (s1) { asm volatile("s_waitcnt vmcnt(4)" ::: "memory"); }
    else    { asm volatile("s_waitcnt vmcnt(0)" ::: "memory"); }
    BAR;
    LD_A(cur, 1, af1);
    if (s1) ST_B(nxt, 1, t + 1);
    SCHB;
    __builtin_amdgcn_s_setprio(1); QMM(0, 1, af0, bB); __builtin_amdgcn_s_setprio(0);
    if (s1) { asm volatile("s_waitcnt vmcnt(2)" ::: "memory"); }
    BAR;
    if (s1) ST_A(nxt, 1, t + 1);
    SCHB;
    __builtin_amdgcn_s_setprio(1); QMM(1, 0, af1, bA); __builtin_amdgcn_s_setprio(0);
    if (s1) LD_B(nxt, 0, bA);
    BAR;
    if (s1) LD_A(nxt, 0, af0);
    SCHB;
    __builtin_amdgcn_s_setprio(1); QMM(1, 1, af1, bB); __builtin_amdgcn_s_setprio(0);
    if (s1) { asm volatile("s_waitcnt vmcnt(2)" ::: "memory"); }
    BAR;
  }

  // ---- fused LSTM epilogue. C/D layout: col=l16, row=quad*4+reg [m89/m91].
  // block's hN footprint: 256 agents x 64 hids, hid0 = tileN/4; local hid = wn*16+l16.
  const int cb0 = (int)tileN + wn * 64;
  const int hid0 = (int)(tileN >> 2);
  const int bid = lin;
  float bcv[4], qv[4];
#pragma unroll
  for (int g = 0; g < 4; ++g) {
    bcv[g] = bc[cb0 + g * 16 + l16];
    qv[g]  = (MODE == 11) ? q[cb0 + g * 16 + l16] : 0.f;
  }
  unsigned short* hlds = As;  // 32KB of As reused (safe after final BAR)
  float sacc = 0.f;
#pragma unroll
  for (int mf = 0; mf < 8; ++mf) {
    long ag0 = tileM + wm * 128 + mf * 16 + quad * 4;
#pragma unroll
    for (int r = 0; r < 4; ++r) {
      long ag = ag0 + r;
      const size_t pk = ((size_t)bid * 32 + (mf * 4 + r)) * 512 + tid;  // packed slot
      float zi = acc[mf][0][r], zf = acc[mf][1][r];
      float zg = acc[mf][2][r], zo = acc[mf][3][r];
      if (MODE == 10) {
        s16x4 ev;
        ev[0] = (short)f2bf(zi); ev[1] = (short)f2bf(zf);
        ev[2] = (short)f2bf(zg); ev[3] = (short)f2bf(zo);
        *(s16x4*)&E1b[pk * 4] = ev;
        zi += bcv[0]; zf += bcv[1]; zg += bcv[2]; zo += bcv[3];
      } else {
        s16x4 ev = *(const s16x4*)&E1b[pk * 4];
        zi += bf2f((unsigned short)ev[0]) + qv[0] + bcv[0];
        zf += bf2f((unsigned short)ev[1]) + qv[1] + bcv[1];
        zg += bf2f((unsigned short)ev[2]) + qv[2] + bcv[2];
        zo += bf2f((unsigned short)ev[3]) + qv[3] + bcv[3];
      }
      float cold = (MODE == 10) ? 0.f : cell[pk];
      float cnew = fsigm(zf) * cold + fsigm(zi) * ftanh(zg);
      float hv   = fsigm(zo) * ftanh(cnew);
      cell[pk] = cnew;
      // stage into LDS: row = local agent, col = local hid
      hlds[(wm * 128 + mf * 16 + quad * 4 + r) * 64 + (wn * 16 + l16)] = f2bf(hv);
      if (ACCS) sacc += alive[ag] * hv;
    }
  }
  if (ACCS) {
    sacc += __shfl_xor(sacc, 16);
    sacc += __shfl_xor(sacc, 32);
    if (quad == 0) atomicAdd(&S[hid0 + wn * 16 + l16], sacc);
  }
  __syncthreads();  // LDS tile complete (inserts lgkmcnt drain)
  // coalesced hN writeback: 2048 x 16B chunks, 4 per thread, lane-contiguous
#pragma unroll
  for (int k2 = 0; k2 < 4; ++k2) {
    int ci = tid + 512 * k2;           // 0..2047
    int row = ci >> 3, c8 = ci & 7;
    s16x8 v = *(const s16x8*)&hlds[ci * 8];
    *(s16x8*)&hN[(tileM + row) * HID + hid0 + c8 * 8] = v;
  }
#undef ST_A
#undef ST_B
#undef LD_A
#undef LD_B
#undef QMM
#undef BAR
#undef SCHB
}

// ---------------- bf16 MFMA GEMM, dbuf global_load_lds pipeline (one barrier/K-iter).
// Small-grid shapes. C(MxN) = A(MxK,row) * B(NxK,row)^T. grid x = B-tiles, y = A-tiles,
// z = K-split (koff = blockIdx.z*K). MODE 1: bf16(tanh(acc+bias[col])) (encoder,
// XCD-swizzled). MODE 2: f32 atomicAdd into Cf (head split-K; Cf pre-zeroed).
template <int MODE>
__global__ __launch_bounds__(256, 4) void gemm_bt(
    const unsigned short* __restrict__ A, const unsigned short* __restrict__ B,
    int K, int lda, int ldb,
    unsigned short* __restrict__ Cb, float* __restrict__ Cf, int ldc,
    const float* __restrict__ bias)
{
  __shared__ __align__(16) unsigned short As0[2 * 128 * 32];
  __shared__ __align__(16) unsigned short Bs0[2 * 128 * 32];
  const int tid  = threadIdx.x;
  const int lane = tid & 63;
  const int wave = tid >> 6;
  const int wm = wave >> 1, wn = wave & 1;
  const int quad = lane >> 4, l16 = lane & 15;
  // XCD swizzle for MODE 1 (encoder, 16x16 grid); head (MODE 2) unswizzled
  int bxs = (int)blockIdx.x, bys = (int)blockIdx.y;
  if (MODE == 1) {
    int lin = (int)blockIdx.x + (int)blockIdx.y * (int)gridDim.x;
    bys = lin % (int)gridDim.y;
    bxs = lin / (int)gridDim.y;
  }
  const long tileM = (long)bys * 128;
  const long tileN = (long)bxs * 128;
  const long koff  = (long)blockIdx.z * K;

  const int srow = lane >> 2;
  const int skc  = (lane & 3) * 8;
  const unsigned short* gA = &A[(tileM + wave * 32 + srow) * lda + koff + skc];
  const unsigned short* gB = &B[(tileN + wave * 32 + srow) * ldb + koff + skc];
  const int ldsOff = wave * 32 * 32;

  f32x4 acc[4][4] = {};
  const int nIt = K >> 5;

  gload16(gA, &As0[ldsOff]);
  gload16(gA + 16 * lda, &As0[ldsOff + 16 * 32]);
  gload16(gB, &Bs0[ldsOff]);
  gload16(gB + 16 * ldb, &Bs0[ldsOff + 16 * 32]);

  for (int i = 0; i < nIt; ++i) {
    __syncthreads();
    const int cb = (i & 1) * 4096;
    if (i + 1 < nIt) {
      const int nb = ((i + 1) & 1) * 4096;
      const long ko = (long)(i + 1) * 32;
      gload16(gA + ko, &As0[nb + ldsOff]);
      gload16(gA + ko + 16 * lda, &As0[nb + ldsOff + 16 * 32]);
      gload16(gB + ko, &Bs0[nb + ldsOff]);
      gload16(gB + ko + 16 * ldb, &Bs0[nb + ldsOff + 16 * 32]);
    }
    s16x8 af[4], bfr[4];
#pragma unroll
    for (int ii = 0; ii < 4; ++ii)
      af[ii] = *(const s16x8*)&As0[cb + (wm * 64 + ii * 16 + l16) * 32 + quad * 8];
#pragma unroll
    for (int j = 0; j < 4; ++j)
      bfr[j] = *(const s16x8*)&Bs0[cb + (wn * 64 + j * 16 + l16) * 32 + quad * 8];
#pragma unroll
    for (int ii = 0; ii < 4; ++ii)
#pragma unroll
      for (int j = 0; j < 4; ++j)
        acc[ii][j] = __builtin_amdgcn_mfma_f32_16x16x32_bf16(af[ii], bfr[j], acc[ii][j], 0, 0, 0);
  }

#pragma unroll
  for (int i = 0; i < 4; ++i) {
    long r0 = tileM + wm * 64 + i * 16 + quad * 4;
#pragma unroll
    for (int j = 0; j < 4; ++j) {
      long col = tileN + wn * 64 + j * 16 + l16;
      float bv = (MODE == 1) ? bias[col] : 0.f;
#pragma unroll
      for (int r = 0; r < 4; ++r) {
        float v = acc[i][j][r];
        if (MODE == 1) { v = ftanh(v + bv); Cb[(r0 + r) * ldc + col] = f2bf(v); }
        if (MODE == 2) atomicAdd(&Cf[(r0 + r) * ldc + col], v);
      }
    }
  }
}

// ---------------- merged prep kernel: buildw + cvt + build_whd + biasmix + zeros.
// Segmented grid; all segments independent (nalive runs in the prior dispatch).
// Block counts: buildw GATES*HID/4/256 = 16384; cvt N_AG*OBSD/4/256 = 2048;
// whd 128*HID/4/256 = 256 (R7 fix: was 128 -> Whd rows 64..127 stale -> value wrong);
// bias GATES/256 = 32; zh N_AG*128/4/256 = 256; S 2*HID/4/256 = 4.
#define PB_BUILDW  16384
#define PB_CVT     2048
#define PB_WHD     256
#define PB_BIAS    32
#define PB_ZH      256
#define PB_S       4
#define PB_TOTAL   (PB_BUILDW + PB_CVT + PB_WHD + PB_BIAS + PB_ZH + PB_S)
__global__ void prep(const float* __restrict__ w_ih, const float* __restrict__ w_hh,
                     const float* __restrict__ nA,
                     unsigned short* __restrict__ Wihb, unsigned short* __restrict__ W2b,
                     const float* __restrict__ obs, unsigned short* __restrict__ obsb,
                     const float* __restrict__ enc_w, unsigned short* __restrict__ encb,
                     const float* __restrict__ act_w, const float* __restrict__ val_w,
                     unsigned short* __restrict__ whd,
                     const float* __restrict__ b_ih, const float* __restrict__ b_hh,
                     float* __restrict__ bc, float* __restrict__ zh,
                     float* __restrict__ S12) {
  int b = blockIdx.x;
  if (b < PB_BUILDW) {
    // weights, GATE-INTERLEAVED rows: out row c <- src row g*HID+hid,
    // g=(c>>4)&3, hid=((c>>6)<<4)|(c&15). W2b folds the comm term: w_hh - s*w_ih.
    int i = b * 256 + threadIdx.x;
    float s = 1.0f / (nA[0] - 1.0f);
    int c  = i >> 9;
    int kk = (i & 511) * 4;
    int g   = (c >> 4) & 3;
    int hid = ((c >> 6) << 4) | (c & 15);
    size_t src = ((size_t)g * HID + hid) * HID + kk;
    size_t dst = (size_t)c * HID + kk;
    f32x4 a = *(const f32x4*)&w_ih[src];
    f32x4 bb = *(const f32x4*)&w_hh[src];
    s16x4 oa, ob;
#pragma unroll
    for (int e = 0; e < 4; ++e) {
      oa[e] = (short)f2bf(a[e]);
      ob[e] = (short)f2bf(bb[e] - s * a[e]);
    }
    *(s16x4*)&Wihb[dst] = oa;
    *(s16x4*)&W2b[dst] = ob;
  } else if (b < PB_BUILDW + PB_CVT) {
    int i = (b - PB_BUILDW) * 256 + threadIdx.x;
    f32x4 a = ((const f32x4*)obs)[i];
    f32x4 bb = ((const f32x4*)enc_w)[i];
    s16x4 oa, ob;
#pragma unroll
    for (int c = 0; c < 4; ++c) { oa[c] = (short)f2bf(a[c]); ob[c] = (short)f2bf(bb[c]); }
    ((s16x4*)obsb)[i] = oa;
    ((s16x4*)encb)[i] = ob;
  } else if (b < PB_BUILDW + PB_CVT + PB_WHD) {
    // head weights: row 0..63 = act_w, 64 = val_w, 65..127 = 0
    int i = (b - PB_BUILDW - PB_CVT) * 256 + threadIdx.x;
    int r = i >> 9;
    int k = (i & 511) * 4;
    f32x4 v = {0.f, 0.f, 0.f, 0.f};
    if (r < 64)       v = *(const f32x4*)&act_w[(size_t)r * HID + k];
    else if (r == 64) v = *(const f32x4*)&val_w[k];
    s16x4 o;
    o[0] = (short)f2bf(v[0]); o[1] = (short)f2bf(v[1]);
    o[2] = (short)f2bf(v[2]); o[3] = (short)f2bf(v[3]);
    *(s16x4*)&whd[(size_t)r * HID + k] = o;
  } else if (b < PB_BUILDW + PB_CVT + PB_WHD + PB_BIAS) {
    // combined bias, interleaved
    int i = (b - PB_BUILDW - PB_CVT - PB_WHD) * 256 + threadIdx.x;
    int g   = (i >> 4) & 3;
    int hid = ((i >> 6) << 4) | (i & 15);
    int src = g * HID + hid;
    bc[i] = b_ih[src] + b_hh[src];
  } else if (b < PB_BUILDW + PB_CVT + PB_WHD + PB_BIAS + PB_ZH) {
    int i = (b - PB_BUILDW - PB_CVT - PB_WHD - PB_BIAS) * 256 + threadIdx.x;
    f32x4 z = {0.f, 0.f, 0.f, 0.f};
    ((f32x4*)zh)[i] = z;
  } else {
    int i = (b - PB_BUILDW - PB_CVT - PB_WHD - PB_BIAS - PB_ZH) * 256 + threadIdx.x;
    f32x4 z = {0.f, 0.f, 0.f, 0.f};
    ((f32x4*)S12)[i] = z;
  }
}

// ---------------- n_alive reduction
__global__ void nalive_k(const float* __restrict__ alive, float* __restrict__ nA) {
  __shared__ float red[256];
  float s = 0.f;
  for (int i = threadIdx.x; i < N_AG; i += 256) s += alive[i];
  red[threadIdx.x] = s;
  __syncthreads();
  for (int st = 128; st > 0; st >>= 1) {
    if (threadIdx.x < st) red[threadIdx.x] += red[threadIdx.x + st];
    __syncthreads();
  }
  if (threadIdx.x == 0) nA[0] = red[0];
}

// ---------------- GEMV: q[c] = sum_k Wihb[c][k]*S[k] / (nA-1)  (rows interleaved)
__global__ __launch_bounds__(256) void gemv_q(const unsigned short* __restrict__ Wihb,
                                              const float* __restrict__ S,
                                              const float* __restrict__ nA,
                                              float* __restrict__ q) {
  __shared__ float Sl[HID];
  int tid = threadIdx.x, lane = tid & 63, wave = tid >> 6;
  for (int k = tid; k < HID; k += 256) Sl[k] = S[k];
  __syncthreads();
  int g = blockIdx.x * 4 + wave;
  const unsigned short* wr = Wihb + (size_t)g * HID;
  float acc = 0.f;
#pragma unroll
  for (int c = 0; c < 4; ++c) {
    int k = c * 512 + lane * 8;
    s16x8 w = *(const s16x8*)&wr[k];
#pragma unroll
    for (int e = 0; e < 8; ++e) acc += bf2f((unsigned short)w[e]) * Sl[k + e];
  }
  for (int off = 32; off; off >>= 1) acc += __shfl_xor(acc, off);
  if (lane == 0) q[g] = acc / (nA[0] - 1.0f);
}

// ---------------- head epilogue: log_softmax over 64 logits + value; 1 wave/agent
__global__ __launch_bounds__(256) void head_ep(const float* __restrict__ zh,
                                               const float* __restrict__ act_b,
                                               const float* __restrict__ val_b,
                                               float* __restrict__ out) {
  int wave = threadIdx.x >> 6, lane = threadIdx.x & 63;
  int row = blockIdx.x * 4 + wave;
  const float* zr = zh + (size_t)row * 128;
  float a = zr[lane] + act_b[lane];
  float m = a;
  for (int off = 32; off; off >>= 1) m = fmaxf(m, __shfl_xor(m, off));
  float ex = expf(a - m), s = ex;
  for (int off = 32; off; off >>= 1) s += __shfl_xor(s, off);
  out[(size_t)row * ACT + lane] = a - m - logf(s);
  if (lane == 0) out[(size_t)N_AG * ACT + row] = zr[64] + val_b[0];
}

extern "C" void kernel_launch(void* const* d_in, const int* in_sizes, int n_in,
                              void* d_out, int out_size, void* d_ws, size_t ws_size,
                              hipStream_t stream) {
  const float* obs   = (const float*)d_in[0];
  const float* alive = (const float*)d_in[1];
  const float* enc_w = (const float*)d_in[2];
  const float* enc_b = (const float*)d_in[3];
  // d_in[4] g_w, d_in[5] g_b unused: gate = ceil(sigmoid(.)) == 1 identically
  const float* w_ih  = (const float*)d_in[6];
  const float* w_hh  = (const float*)d_in[7];
  const float* b_ih  = (const float*)d_in[8];
  const float* b_hh  = (const float*)d_in[9];
  const float* act_w = (const float*)d_in[10];
  const float* act_b = (const float*)d_in[11];
  const float* val_w = (const float*)d_in[12];
  const float* val_b = (const float*)d_in[13];
  float* out = (float*)d_out;

  char* p = (char*)d_ws;
  unsigned short* Wihb = (unsigned short*)p; p += (size_t)GATES * HID * 2;  // 32 MB
  unsigned short* W2b  = (unsigned short*)p; p += (size_t)GATES * HID * 2;  // 32 MB
  unsigned short* E1b  = (unsigned short*)p; p += (size_t)N_AG * GATES * 2; // 32 MB (packed)
  unsigned short* obsb = (unsigned short*)p; p += (size_t)N_AG * OBSD * 2;  // 4 MB
  unsigned short* encb = (unsigned short*)p; p += (size_t)HID * OBSD * 2;   // 4 MB
  unsigned short* eb   = (unsigned short*)p; p += (size_t)N_AG * HID * 2;   // 8 MB
  unsigned short* h0   = (unsigned short*)p; p += (size_t)N_AG * HID * 2;   // 8 MB
  unsigned short* h1   = (unsigned short*)p; p += (size_t)N_AG * HID * 2;   // 8 MB
  unsigned short* Whd  = (unsigned short*)p; p += (size_t)128 * HID * 2;    // 512 KB
  float* cell = (float*)p; p += (size_t)N_AG * HID * 4;                     // 16 MB (packed)
  float* zh   = (float*)p; p += (size_t)N_AG * 128 * 4;                     // 1 MB
  float* bc   = (float*)p; p += GATES * 4;
  float* q    = (float*)p; p += GATES * 4;
  float* S12  = (float*)p; p += 2 * HID * 4;   // S1 (after iter0), S2 (after iter1)
  float* nA   = (float*)p; p += 256;
  float* S1 = S12, *S2 = S12 + HID;

  nalive_k<<<1, 256, 0, stream>>>(alive, nA);
  prep<<<PB_TOTAL, 256, 0, stream>>>(w_ih, w_hh, nA, Wihb, W2b, obs, obsb, enc_w, encb,
                                     act_w, val_w, Whd, b_ih, b_hh, bc, zh, S12);

  // encoder: eb = bf16(tanh(obs @ enc_w^T + enc_b))
  gemm_bt<1><<<dim3(HID / 128, N_AG / 128), 256, 0, stream>>>(
      obsb, encb, OBSD, OBSD, OBSD, eb, nullptr, HID, enc_b);

  // iter 0 fused: E1 = e @ Wih^T (packed store) + LSTM(c=0) -> cell, h0; S1 += alive*h0
  gemm256<10, 1><<<dim3(GATES / 256, N_AG / 256), 512, 0, stream>>>(
      eb, Wihb, HID, HID, HID, E1b, nullptr, bc, cell, h0, alive, S1);

  // iter 1 fused: z2 = h0 @ W2^T + E1 + q + bc -> LSTM -> cell, h1; S2 += alive*h1
  gemv_q<<<GATES / 4, 256, 0, stream>>>(Wihb, S1, nA, q);
  gemm256<11, 1><<<dim3(GATES / 256, N_AG / 256), 512, 0, stream>>>(
      h0, W2b, HID, HID, HID, E1b, q, bc, cell, h1, alive, S2);

  // iter 2 fused (no S accumulation)
  gemv_q<<<GATES / 4, 256, 0, stream>>>(Wihb, S2, nA, q);
  gemm256<11, 0><<<dim3(GATES / 256, N_AG / 256), 512, 0, stream>>>(
      h1, W2b, HID, HID, HID, E1b, q, bc, cell, h0, alive, nullptr);

  // head: zh(2048x128) = h @ Whd^T, split-K x8 via f32 atomics (128 blocks)
  gemm_bt<2><<<dim3(1, N_AG / 128, 8), 256, 0, stream>>>(
      h0, Whd, HID / 8, HID, HID, nullptr, zh, 128, nullptr);
  head_ep<<<N_AG / 4, 256, 0, stream>>>(zh, act_b, val_b, out);
}

// Round 9
// 475.080 us; speedup vs baseline: 1.0529x; 1.0529x over previous
//
#include <hip/hip_runtime.h>
#include <cmath>

#define N_AG 2048
#define HID  2048
#define OBSD 1024
#define ACT  64
#define GATES (4*HID)   // 8192

typedef short s16x8 __attribute__((ext_vector_type(8)));
typedef short s16x4 __attribute__((ext_vector_type(4)));
typedef float f32x4 __attribute__((ext_vector_type(4)));

__device__ __forceinline__ unsigned short f2bf(float f) {
  union { float f; unsigned u; } v; v.f = f;
  return (unsigned short)((v.u + 0x7FFFu + ((v.u >> 16) & 1u)) >> 16);
}
__device__ __forceinline__ float bf2f(unsigned short u) {
  union { float f; unsigned u; } v; v.u = ((unsigned)u) << 16;
  return v.f;
}
// Fast transcendentals: native v_exp_f32 + v_rcp_f32. Overflow-safe at all x
// (exp->inf => rcp=0 => correct saturation).
__device__ __forceinline__ float fsigm(float x) {
  return __builtin_amdgcn_rcpf(1.0f + __expf(-x));
}
__device__ __forceinline__ float ftanh(float x) {
  return 2.0f * __builtin_amdgcn_rcpf(1.0f + __expf(-2.0f * x)) - 1.0f;
}

// async global->LDS DMA, 16B per lane; LDS dest = wave-uniform base + lane*16
__device__ __forceinline__ void gload16(const unsigned short* g, unsigned short* l) {
  __builtin_amdgcn_global_load_lds(
      (const __attribute__((address_space(1))) void*)g,
      (__attribute__((address_space(3))) void*)l, 16, 0, 0);
}

// Gate-interleaved column index: c = (hid>>4)*64 + g*16 + (hid&15).
// Inverse: g = (c>>4)&3, hid = ((c>>6)<<4) | (c&15).
// Within a wave's 64-col strip the 4 gates of one hid sit at nf=0..3, SAME l16 ->
// the LSTM pointwise is per-lane in the GEMM epilogue (no cross-lane traffic).

// =====================================================================================
// 256x256 bf16 GEMM + fused LSTM epilogue + fused comm column-sum.
// C = A(MxK,row) * B(NxK,row)^T. 512 thr = 8 waves (2M x 4N), BK=64, LDS dbuf, 1 blk/CU.
// R8: DEFAULT block mapping restored. R7's XCD swizzle (tileM=lin&7) gave each XCD one
//  L2-resident A-panel but streamed ALL 32 B-panels (32MB) through its 4MB L2:
//  FETCH 75->160MB, dur 93->108us. Default mapping (lin = bx + by*32, XCD = lin%8)
//  already gives each XCD only 4 distinct B-panels (4MB = L2-resident) with A via L3.
// Kept from R6/R7: hN store via LDS bounce (2048 contiguous 16B stores vs 16384
//  scattered 2B); packed private E1b/cell ([bid][slot][tid], coalesced); merged prep.
// MODE 10 (iter 0): store E1 (packed); LSTM c_old=0, z=acc+bc; write cell, hN.
// MODE 11 (iters 1,2): z = acc + E1 + q + bc; LSTM step; write cell, hN.
// ACCS: S[hid] += alive[ag]*h_new (quad-reduced, 1 atomic/4 lanes).
// LAST (R8): final iteration -> cell never read again -> skip the 16MB cell store.
// =====================================================================================
template <int MODE, int ACCS, int LAST>
__global__ __launch_bounds__(512, 2) void gemm256(
    const unsigned short* __restrict__ A, const unsigned short* __restrict__ B,
    int K, int lda, int ldb,
    unsigned short* __restrict__ E1b, const float* __restrict__ q,
    const float* __restrict__ bc, float* __restrict__ cell,
    unsigned short* __restrict__ hN,
    const float* __restrict__ alive, float* __restrict__ S)
{
  __shared__ __align__(16) unsigned short As[32768];  // 64 KiB
  __shared__ __align__(16) unsigned short Bs[32768];  // 64 KiB

  const int tid  = threadIdx.x;
  const int lane = tid & 63;
  const int wave = tid >> 6;                 // 0..7
  const int wm   = wave >> 2, wn = wave & 3; // 2M x 4N wave grid
  const int quad = lane >> 4, l16 = lane & 15, r7 = lane & 7;
  // default mapping (R8 revert): per-XCD working set = 4 B-panels (L2-resident)
  const int lin  = (int)blockIdx.x + (int)blockIdx.y * (int)gridDim.x;
  const long tileM = (long)blockIdx.y * 256;
  const long tileN = (long)blockIdx.x * 256;

  // staging; col pre-swizzled: global col-block (lane&7)^(lane>>3) -> LDS slot g^(row&7)
  const unsigned scol  = (((lane & 7) ^ (lane >> 3)) * 8u);
  const unsigned aoffL = (unsigned)(tileM + wave * 8 + (lane >> 3)) * (unsigned)lda + scol;
  const unsigned boffL = (unsigned)(tileN + (wave >> 2) * 64 + (wave & 3) * 8 + (lane >> 3))
                           * (unsigned)ldb + scol;

#define ST_A(d, h, t) { \
    gload16(A + aoffL + (unsigned)((h) * 64) * (unsigned)lda + (unsigned)(t) * 64u, \
            &As[(d) * 16384 + (h) * 8192 + wave * 512]); \
    gload16(A + aoffL + (unsigned)(128 + (h) * 64) * (unsigned)lda + (unsigned)(t) * 64u, \
            &As[(d) * 16384 + (h) * 8192 + wave * 512 + 4096]); }
#define ST_B(d, h, t) { \
    gload16(B + boffL + (unsigned)((h) * 32) * (unsigned)ldb + (unsigned)(t) * 64u, \
            &Bs[(d) * 16384 + (h) * 8192 + wave * 512]); \
    gload16(B + boffL + (unsigned)(128 + (h) * 32) * (unsigned)ldb + (unsigned)(t) * 64u, \
            &Bs[(d) * 16384 + (h) * 8192 + wave * 512 + 4096]); }

  const int ax = wm * 4096 + l16 * 64;       // within A half region (elems)
  const int bx = wn * 2048 + l16 * 64;       // within B half region
  const int c0 = (quad ^ r7) * 8;            // swizzled col, K-step 0
  const int c1 = ((4 + quad) ^ r7) * 8;      // swizzled col, K-step 1

  s16x8 af0[4][2], af1[4][2], bA[2][2], bB[2][2];
  f32x4 acc[8][4] = {};

#define LD_A(d, Mh, dst) { const unsigned short* p_ = &As[(d) * 16384 + (Mh) * 8192 + ax]; \
    _Pragma("unroll") for (int ml = 0; ml < 4; ++ml) { \
      dst[ml][0] = *(const s16x8*)(p_ + ml * 1024 + c0); \
      dst[ml][1] = *(const s16x8*)(p_ + ml * 1024 + c1); } }
#define LD_B(d, Nh, dst) { const unsigned short* p_ = &Bs[(d) * 16384 + (Nh) * 8192 + bx]; \
    _Pragma("unroll") for (int nl = 0; nl < 2; ++nl) { \
      dst[nl][0] = *(const s16x8*)(p_ + nl * 1024 + c0); \
      dst[nl][1] = *(const s16x8*)(p_ + nl * 1024 + c1); } }
#define QMM(Mh, Nh, afv, bb) \
    _Pragma("unroll") for (int ks = 0; ks < 2; ++ks) \
    _Pragma("unroll") for (int ml = 0; ml < 4; ++ml) \
    _Pragma("unroll") for (int nl = 0; nl < 2; ++nl) \
      acc[(Mh) * 4 + ml][(Nh) * 2 + nl] = __builtin_amdgcn_mfma_f32_16x16x32_bf16( \
          afv[ml][ks], bb[nl][ks], acc[(Mh) * 4 + ml][(Nh) * 2 + nl], 0, 0, 0);
#define BAR  __builtin_amdgcn_s_barrier()
#define SCHB __builtin_amdgcn_sched_barrier(0)

  const int NT = K >> 6;   // K-tiles of 64

  ST_B(0, 0, 0); ST_A(0, 0, 0); ST_B(0, 1, 0); ST_A(0, 1, 0);
  asm volatile("s_waitcnt vmcnt(0)" ::: "memory");
  BAR;
  LD_A(0, 0, af0); LD_B(0, 0, bA);

  for (int t = 0; t < NT; ++t) {
    const int cur = t & 1, nxt = cur ^ 1;
    const bool s1 = (t + 1 < NT);
    LD_B(cur, 1, bB);
    if (s1) { ST_B(nxt, 0, t + 1); ST_A(nxt, 0, t + 1); }
    SCHB;
    __builtin_amdgcn_s_setprio(1); QMM(0, 0, af0, bA); __builtin_amdgcn_s_setprio(0);
    if (s1) { asm volatile("s_waitcnt vmcnt(4)" ::: "memory"); }
    else    { asm volatile("s_waitcnt vmcnt(0)" ::: "memory"); }
    BAR;
    LD_A(cur, 1, af1);
    if (s1) ST_B(nxt, 1, t + 1);
    SCHB;
    __builtin_amdgcn_s_setprio(1); QMM(0, 1, af0, bB); __builtin_amdgcn_s_setprio(0);
    if (s1) { asm volatile("s_waitcnt vmcnt(2)" ::: "memory"); }
    BAR;
    if (s1) ST_A(nxt, 1, t + 1);
    SCHB;
    __builtin_amdgcn_s_setprio(1); QMM(1, 0, af1, bA); __builtin_amdgcn_s_setprio(0);
    if (s1) LD_B(nxt, 0, bA);
    BAR;
    if (s1) LD_A(nxt, 0, af0);
    SCHB;
    __builtin_amdgcn_s_setprio(1); QMM(1, 1, af1, bB); __builtin_amdgcn_s_setprio(0);
    if (s1) { asm volatile("s_waitcnt vmcnt(2)" ::: "memory"); }
    BAR;
  }

  // ---- fused LSTM epilogue. C/D layout: col=l16, row=quad*4+reg [m89/m91].
  // block's hN footprint: 256 agents x 64 hids, hid0 = tileN/4; local hid = wn*16+l16.
  const int cb0 = (int)tileN + wn * 64;
  const int hid0 = (int)(tileN >> 2);
  const int bid = lin;
  float bcv[4], qv[4];
#pragma unroll
  for (int g = 0; g < 4; ++g) {
    bcv[g] = bc[cb0 + g * 16 + l16];
    qv[g]  = (MODE == 11) ? q[cb0 + g * 16 + l16] : 0.f;
  }
  unsigned short* hlds = As;  // 32KB of As reused (safe after final BAR)
  float sacc = 0.f;
#pragma unroll
  for (int mf = 0; mf < 8; ++mf) {
    long ag0 = tileM + wm * 128 + mf * 16 + quad * 4;
#pragma unroll
    for (int r = 0; r < 4; ++r) {
      long ag = ag0 + r;
      const size_t pk = ((size_t)bid * 32 + (mf * 4 + r)) * 512 + tid;  // packed slot
      float zi = acc[mf][0][r], zf = acc[mf][1][r];
      float zg = acc[mf][2][r], zo = acc[mf][3][r];
      if (MODE == 10) {
        s16x4 ev;
        ev[0] = (short)f2bf(zi); ev[1] = (short)f2bf(zf);
        ev[2] = (short)f2bf(zg); ev[3] = (short)f2bf(zo);
        *(s16x4*)&E1b[pk * 4] = ev;
        zi += bcv[0]; zf += bcv[1]; zg += bcv[2]; zo += bcv[3];
      } else {
        s16x4 ev = *(const s16x4*)&E1b[pk * 4];
        zi += bf2f((unsigned short)ev[0]) + qv[0] + bcv[0];
        zf += bf2f((unsigned short)ev[1]) + qv[1] + bcv[1];
        zg += bf2f((unsigned short)ev[2]) + qv[2] + bcv[2];
        zo += bf2f((unsigned short)ev[3]) + qv[3] + bcv[3];
      }
      float cold = (MODE == 10) ? 0.f : cell[pk];
      float cnew = fsigm(zf) * cold + fsigm(zi) * ftanh(zg);
      float hv   = fsigm(zo) * ftanh(cnew);
      if (!LAST) cell[pk] = cnew;   // final iter: cell never read again
      // stage into LDS: row = local agent, col = local hid
      hlds[(wm * 128 + mf * 16 + quad * 4 + r) * 64 + (wn * 16 + l16)] = f2bf(hv);
      if (ACCS) sacc += alive[ag] * hv;
    }
  }
  if (ACCS) {
    sacc += __shfl_xor(sacc, 16);
    sacc += __shfl_xor(sacc, 32);
    if (quad == 0) atomicAdd(&S[hid0 + wn * 16 + l16], sacc);
  }
  __syncthreads();  // LDS tile complete (inserts lgkmcnt drain)
  // coalesced hN writeback: 2048 x 16B chunks, 4 per thread, lane-contiguous
#pragma unroll
  for (int k2 = 0; k2 < 4; ++k2) {
    int ci = tid + 512 * k2;           // 0..2047
    int row = ci >> 3, c8 = ci & 7;
    s16x8 v = *(const s16x8*)&hlds[ci * 8];
    *(s16x8*)&hN[(tileM + row) * HID + hid0 + c8 * 8] = v;
  }
#undef ST_A
#undef ST_B
#undef LD_A
#undef LD_B
#undef QMM
#undef BAR
#undef SCHB
}

// ---------------- bf16 MFMA GEMM, dbuf global_load_lds pipeline (one barrier/K-iter).
// Small-grid shapes. C(MxN) = A(MxK,row) * B(NxK,row)^T. grid x = B-tiles, y = A-tiles,
// z = K-split (koff = blockIdx.z*K). MODE 1: bf16(tanh(acc+bias[col])) (encoder).
// MODE 2: f32 atomicAdd into Cf (head split-K; Cf pre-zeroed). Default block mapping.
template <int MODE>
__global__ __launch_bounds__(256, 4) void gemm_bt(
    const unsigned short* __restrict__ A, const unsigned short* __restrict__ B,
    int K, int lda, int ldb,
    unsigned short* __restrict__ Cb, float* __restrict__ Cf, int ldc,
    const float* __restrict__ bias)
{
  __shared__ __align__(16) unsigned short As0[2 * 128 * 32];
  __shared__ __align__(16) unsigned short Bs0[2 * 128 * 32];
  const int tid  = threadIdx.x;
  const int lane = tid & 63;
  const int wave = tid >> 6;
  const int wm = wave >> 1, wn = wave & 1;
  const int quad = lane >> 4, l16 = lane & 15;
  const long tileM = (long)blockIdx.y * 128;
  const long tileN = (long)blockIdx.x * 128;
  const long koff  = (long)blockIdx.z * K;

  const int srow = lane >> 2;
  const int skc  = (lane & 3) * 8;
  const unsigned short* gA = &A[(tileM + wave * 32 + srow) * lda + koff + skc];
  const unsigned short* gB = &B[(tileN + wave * 32 + srow) * ldb + koff + skc];
  const int ldsOff = wave * 32 * 32;

  f32x4 acc[4][4] = {};
  const int nIt = K >> 5;

  gload16(gA, &As0[ldsOff]);
  gload16(gA + 16 * lda, &As0[ldsOff + 16 * 32]);
  gload16(gB, &Bs0[ldsOff]);
  gload16(gB + 16 * ldb, &Bs0[ldsOff + 16 * 32]);

  for (int i = 0; i < nIt; ++i) {
    __syncthreads();
    const int cb = (i & 1) * 4096;
    if (i + 1 < nIt) {
      const int nb = ((i + 1) & 1) * 4096;
      const long ko = (long)(i + 1) * 32;
      gload16(gA + ko, &As0[nb + ldsOff]);
      gload16(gA + ko + 16 * lda, &As0[nb + ldsOff + 16 * 32]);
      gload16(gB + ko, &Bs0[nb + ldsOff]);
      gload16(gB + ko + 16 * ldb, &Bs0[nb + ldsOff + 16 * 32]);
    }
    s16x8 af[4], bfr[4];
#pragma unroll
    for (int ii = 0; ii < 4; ++ii)
      af[ii] = *(const s16x8*)&As0[cb + (wm * 64 + ii * 16 + l16) * 32 + quad * 8];
#pragma unroll
    for (int j = 0; j < 4; ++j)
      bfr[j] = *(const s16x8*)&Bs0[cb + (wn * 64 + j * 16 + l16) * 32 + quad * 8];
#pragma unroll
    for (int ii = 0; ii < 4; ++ii)
#pragma unroll
      for (int j = 0; j < 4; ++j)
        acc[ii][j] = __builtin_amdgcn_mfma_f32_16x16x32_bf16(af[ii], bfr[j], acc[ii][j], 0, 0, 0);
  }

#pragma unroll
  for (int i = 0; i < 4; ++i) {
    long r0 = tileM + wm * 64 + i * 16 + quad * 4;
#pragma unroll
    for (int j = 0; j < 4; ++j) {
      long col = tileN + wn * 64 + j * 16 + l16;
      float bv = (MODE == 1) ? bias[col] : 0.f;
#pragma unroll
      for (int r = 0; r < 4; ++r) {
        float v = acc[i][j][r];
        if (MODE == 1) { v = ftanh(v + bv); Cb[(r0 + r) * ldc + col] = f2bf(v); }
        if (MODE == 2) atomicAdd(&Cf[(r0 + r) * ldc + col], v);
      }
    }
  }
}

// ---------------- merged prep kernel: buildw + cvt + build_whd + biasmix + zeros.
// Segmented grid; all segments independent (nalive runs in the prior dispatch).
// Block counts: buildw GATES*HID/4/256 = 16384; cvt N_AG*OBSD/4/256 = 2048;
// whd 128*HID/4/256 = 256; bias GATES/256 = 32; zh N_AG*128/4/256 = 256; S = 4.
#define PB_BUILDW  16384
#define PB_CVT     2048
#define PB_WHD     256
#define PB_BIAS    32
#define PB_ZH      256
#define PB_S       4
#define PB_TOTAL   (PB_BUILDW + PB_CVT + PB_WHD + PB_BIAS + PB_ZH + PB_S)
__global__ void prep(const float* __restrict__ w_ih, const float* __restrict__ w_hh,
                     const float* __restrict__ nA,
                     unsigned short* __restrict__ Wihb, unsigned short* __restrict__ W2b,
                     const float* __restrict__ obs, unsigned short* __restrict__ obsb,
                     const float* __restrict__ enc_w, unsigned short* __restrict__ encb,
                     const float* __restrict__ act_w, const float* __restrict__ val_w,
                     unsigned short* __restrict__ whd,
                     const float* __restrict__ b_ih, const float* __restrict__ b_hh,
                     float* __restrict__ bc, float* __restrict__ zh,
                     float* __restrict__ S12) {
  int b = blockIdx.x;
  if (b < PB_BUILDW) {
    // weights, GATE-INTERLEAVED rows: out row c <- src row g*HID+hid,
    // g=(c>>4)&3, hid=((c>>6)<<4)|(c&15). W2b folds the comm term: w_hh - s*w_ih.
    int i = b * 256 + threadIdx.x;
    float s = 1.0f / (nA[0] - 1.0f);
    int c  = i >> 9;
    int kk = (i & 511) * 4;
    int g   = (c >> 4) & 3;
    int hid = ((c >> 6) << 4) | (c & 15);
    size_t src = ((size_t)g * HID + hid) * HID + kk;
    size_t dst = (size_t)c * HID + kk;
    f32x4 a = *(const f32x4*)&w_ih[src];
    f32x4 bb = *(const f32x4*)&w_hh[src];
    s16x4 oa, ob;
#pragma unroll
    for (int e = 0; e < 4; ++e) {
      oa[e] = (short)f2bf(a[e]);
      ob[e] = (short)f2bf(bb[e] - s * a[e]);
    }
    *(s16x4*)&Wihb[dst] = oa;
    *(s16x4*)&W2b[dst] = ob;
  } else if (b < PB_BUILDW + PB_CVT) {
    int i = (b - PB_BUILDW) * 256 + threadIdx.x;
    f32x4 a = ((const f32x4*)obs)[i];
    f32x4 bb = ((const f32x4*)enc_w)[i];
    s16x4 oa, ob;
#pragma unroll
    for (int c = 0; c < 4; ++c) { oa[c] = (short)f2bf(a[c]); ob[c] = (short)f2bf(bb[c]); }
    ((s16x4*)obsb)[i] = oa;
    ((s16x4*)encb)[i] = ob;
  } else if (b < PB_BUILDW + PB_CVT + PB_WHD) {
    // head weights: row 0..63 = act_w, 64 = val_w, 65..127 = 0
    int i = (b - PB_BUILDW - PB_CVT) * 256 + threadIdx.x;
    int r = i >> 9;
    int k = (i & 511) * 4;
    f32x4 v = {0.f, 0.f, 0.f, 0.f};
    if (r < 64)       v = *(const f32x4*)&act_w[(size_t)r * HID + k];
    else if (r == 64) v = *(const f32x4*)&val_w[k];
    s16x4 o;
    o[0] = (short)f2bf(v[0]); o[1] = (short)f2bf(v[1]);
    o[2] = (short)f2bf(v[2]); o[3] = (short)f2bf(v[3]);
    *(s16x4*)&whd[(size_t)r * HID + k] = o;
  } else if (b < PB_BUILDW + PB_CVT + PB_WHD + PB_BIAS) {
    // combined bias, interleaved
    int i = (b - PB_BUILDW - PB_CVT - PB_WHD) * 256 + threadIdx.x;
    int g   = (i >> 4) & 3;
    int hid = ((i >> 6) << 4) | (i & 15);
    int src = g * HID + hid;
    bc[i] = b_ih[src] + b_hh[src];
  } else if (b < PB_BUILDW + PB_CVT + PB_WHD + PB_BIAS + PB_ZH) {
    int i = (b - PB_BUILDW - PB_CVT - PB_WHD - PB_BIAS) * 256 + threadIdx.x;
    f32x4 z = {0.f, 0.f, 0.f, 0.f};
    ((f32x4*)zh)[i] = z;
  } else {
    int i = (b - PB_BUILDW - PB_CVT - PB_WHD - PB_BIAS - PB_ZH) * 256 + threadIdx.x;
    f32x4 z = {0.f, 0.f, 0.f, 0.f};
    ((f32x4*)S12)[i] = z;
  }
}

// ---------------- n_alive reduction
__global__ void nalive_k(const float* __restrict__ alive, float* __restrict__ nA) {
  __shared__ float red[256];
  float s = 0.f;
  for (int i = threadIdx.x; i < N_AG; i += 256) s += alive[i];
  red[threadIdx.x] = s;
  __syncthreads();
  for (int st = 128; st > 0; st >>= 1) {
    if (threadIdx.x < st) red[threadIdx.x] += red[threadIdx.x + st];
    __syncthreads();
  }
  if (threadIdx.x == 0) nA[0] = red[0];
}

// ---------------- GEMV: q[c] = sum_k Wihb[c][k]*S[k] / (nA-1)  (rows interleaved)
__global__ __launch_bounds__(256) void gemv_q(const unsigned short* __restrict__ Wihb,
                                              const float* __restrict__ S,
                                              const float* __restrict__ nA,
                                              float* __restrict__ q) {
  __shared__ float Sl[HID];
  int tid = threadIdx.x, lane = tid & 63, wave = tid >> 6;
  for (int k = tid; k < HID; k += 256) Sl[k] = S[k];
  __syncthreads();
  int g = blockIdx.x * 4 + wave;
  const unsigned short* wr = Wihb + (size_t)g * HID;
  float acc = 0.f;
#pragma unroll
  for (int c = 0; c < 4; ++c) {
    int k = c * 512 + lane * 8;
    s16x8 w = *(const s16x8*)&wr[k];
#pragma unroll
    for (int e = 0; e < 8; ++e) acc += bf2f((unsigned short)w[e]) * Sl[k + e];
  }
  for (int off = 32; off; off >>= 1) acc += __shfl_xor(acc, off);
  if (lane == 0) q[g] = acc / (nA[0] - 1.0f);
}

// ---------------- head epilogue: log_softmax over 64 logits + value; 1 wave/agent
__global__ __launch_bounds__(256) void head_ep(const float* __restrict__ zh,
                                               const float* __restrict__ act_b,
                                               const float* __restrict__ val_b,
                                               float* __restrict__ out) {
  int wave = threadIdx.x >> 6, lane = threadIdx.x & 63;
  int row = blockIdx.x * 4 + wave;
  const float* zr = zh + (size_t)row * 128;
  float a = zr[lane] + act_b[lane];
  float m = a;
  for (int off = 32; off; off >>= 1) m = fmaxf(m, __shfl_xor(m, off));
  float ex = expf(a - m), s = ex;
  for (int off = 32; off; off >>= 1) s += __shfl_xor(s, off);
  out[(size_t)row * ACT + lane] = a - m - logf(s);
  if (lane == 0) out[(size_t)N_AG * ACT + row] = zr[64] + val_b[0];
}

extern "C" void kernel_launch(void* const* d_in, const int* in_sizes, int n_in,
                              void* d_out, int out_size, void* d_ws, size_t ws_size,
                              hipStream_t stream) {
  const float* obs   = (const float*)d_in[0];
  const float* alive = (const float*)d_in[1];
  const float* enc_w = (const float*)d_in[2];
  const float* enc_b = (const float*)d_in[3];
  // d_in[4] g_w, d_in[5] g_b unused: gate = ceil(sigmoid(.)) == 1 identically
  const float* w_ih  = (const float*)d_in[6];
  const float* w_hh  = (const float*)d_in[7];
  const float* b_ih  = (const float*)d_in[8];
  const float* b_hh  = (const float*)d_in[9];
  const float* act_w = (const float*)d_in[10];
  const float* act_b = (const float*)d_in[11];
  const float* val_w = (const float*)d_in[12];
  const float* val_b = (const float*)d_in[13];
  float* out = (float*)d_out;

  char* p = (char*)d_ws;
  unsigned short* Wihb = (unsigned short*)p; p += (size_t)GATES * HID * 2;  // 32 MB
  unsigned short* W2b  = (unsigned short*)p; p += (size_t)GATES * HID * 2;  // 32 MB
  unsigned short* E1b  = (unsigned short*)p; p += (size_t)N_AG * GATES * 2; // 32 MB (packed)
  unsigned short* obsb = (unsigned short*)p; p += (size_t)N_AG * OBSD * 2;  // 4 MB
  unsigned short* encb = (unsigned short*)p; p += (size_t)HID * OBSD * 2;   // 4 MB
  unsigned short* eb   = (unsigned short*)p; p += (size_t)N_AG * HID * 2;   // 8 MB
  unsigned short* h0   = (unsigned short*)p; p += (size_t)N_AG * HID * 2;   // 8 MB
  unsigned short* h1   = (unsigned short*)p; p += (size_t)N_AG * HID * 2;   // 8 MB
  unsigned short* Whd  = (unsigned short*)p; p += (size_t)128 * HID * 2;    // 512 KB
  float* cell = (float*)p; p += (size_t)N_AG * HID * 4;                     // 16 MB (packed)
  float* zh   = (float*)p; p += (size_t)N_AG * 128 * 4;                     // 1 MB
  float* bc   = (float*)p; p += GATES * 4;
  float* q    = (float*)p; p += GATES * 4;
  float* S12  = (float*)p; p += 2 * HID * 4;   // S1 (after iter0), S2 (after iter1)
  float* nA   = (float*)p; p += 256;
  float* S1 = S12, *S2 = S12 + HID;

  nalive_k<<<1, 256, 0, stream>>>(alive, nA);
  prep<<<PB_TOTAL, 256, 0, stream>>>(w_ih, w_hh, nA, Wihb, W2b, obs, obsb, enc_w, encb,
                                     act_w, val_w, Whd, b_ih, b_hh, bc, zh, S12);

  // encoder: eb = bf16(tanh(obs @ enc_w^T + enc_b))
  gemm_bt<1><<<dim3(HID / 128, N_AG / 128), 256, 0, stream>>>(
      obsb, encb, OBSD, OBSD, OBSD, eb, nullptr, HID, enc_b);

  // iter 0 fused: E1 = e @ Wih^T (packed store) + LSTM(c=0) -> cell, h0; S1 += alive*h0
  gemm256<10, 1, 0><<<dim3(GATES / 256, N_AG / 256), 512, 0, stream>>>(
      eb, Wihb, HID, HID, HID, E1b, nullptr, bc, cell, h0, alive, S1);

  // iter 1 fused: z2 = h0 @ W2^T + E1 + q + bc -> LSTM -> cell, h1; S2 += alive*h1
  gemv_q<<<GATES / 4, 256, 0, stream>>>(Wihb, S1, nA, q);
  gemm256<11, 1, 0><<<dim3(GATES / 256, N_AG / 256), 512, 0, stream>>>(
      h0, W2b, HID, HID, HID, E1b, q, bc, cell, h1, alive, S2);

  // iter 2 fused: final -> no S accumulation, no cell store
  gemv_q<<<GATES / 4, 256, 0, stream>>>(Wihb, S2, nA, q);
  gemm256<11, 0, 1><<<dim3(GATES / 256, N_AG / 256), 512, 0, stream>>>(
      h1, W2b, HID, HID, HID, E1b, q, bc, cell, h0, alive, nullptr);

  // head: zh(2048x128) = h @ Whd^T, split-K x8 via f32 atomics (128 blocks)
  gemm_bt<2><<<dim3(1, N_AG / 128, 8), 256, 0, stream>>>(
      h0, Whd, HID / 8, HID, HID, nullptr, zh, 128, nullptr);
  head_ep<<<N_AG / 4, 256, 0, stream>>>(zh, act_b, val_b, out);
}